// Round 2
// baseline (751.760 us; speedup 1.0000x reference)
//
#include <hip/hip_runtime.h>
#include <cstdint>
#include <cstddef>

// ---------- types / helpers ----------
typedef float  v4f  __attribute__((ext_vector_type(4)));
typedef __bf16 v8bf __attribute__((ext_vector_type(8)));
typedef __bf16 v4bf __attribute__((ext_vector_type(4)));

__device__ __forceinline__ float b2f(unsigned short u) {
  union { unsigned int i; float f; } cv; cv.i = ((unsigned int)u) << 16; return cv.f;
}
__device__ __forceinline__ unsigned short f2b(float f) {
  union { float f; unsigned int i; } cv; cv.f = f;
  unsigned int i = cv.i;
  i += 0x7fffu + ((i >> 16) & 1u);      // round-to-nearest-even
  return (unsigned short)(i >> 16);
}
__device__ __forceinline__ unsigned short f2b_trunc(float f) {
  union { float f; unsigned int i; } cv; cv.f = f;
  return (unsigned short)(cv.i >> 16);  // truncate (cheap); P only
}
// tanh-form GELU: x*sigmoid(1.59577*(x+0.044715x^3)); |err vs erf-GELU| <= ~3e-4.
__device__ __forceinline__ float gelu_fast(float x) {
  const float u = x * (1.5957691216f + 0.07135481627f * x * x);
  return x * (1.0f / (1.0f + __expf(-u)));
}
__device__ __forceinline__ void g2l16(const unsigned short* g, unsigned short* l) {
  __builtin_amdgcn_global_load_lds(
      (const __attribute__((address_space(1))) void*)g,
      (__attribute__((address_space(3))) void*)l,
      16, 0, 0);
}

// ---------- transpose + fp32->bf16 convert: in[R,C] f32 -> out[C,R] bf16 ----------
__global__ __launch_bounds__(256) void transpose_k(const float* __restrict__ in,
                                                   unsigned short* __restrict__ out,
                                                   int R, int C) {
  __shared__ float tile[32][33];
  const int tx = threadIdx.x, ty = threadIdx.y;
  const int r0 = blockIdx.y * 32, c0 = blockIdx.x * 32;
#pragma unroll
  for (int j = 0; j < 4; ++j)
    tile[ty + 8 * j][tx] = in[(size_t)(r0 + ty + 8 * j) * C + c0 + tx];
  __syncthreads();
#pragma unroll
  for (int j = 0; j < 4; ++j)
    out[(size_t)(c0 + ty + 8 * j) * R + r0 + tx] = f2b(tile[tx][ty + 8 * j]);
}

// ---------- layernorm over DIM=1024 (fp32 or bf16 in, bf16 out) ----------
__global__ __launch_bounds__(256) void ln_kernel(const void* __restrict__ xp, int in_bf16,
                                                 const float* __restrict__ g,
                                                 const float* __restrict__ bta,
                                                 unsigned short* __restrict__ out) {
  const int r = blockIdx.x, t = threadIdx.x;
  float v0, v1, v2, v3;
  if (in_bf16) {
    const ushort4 raw = *(const ushort4*)((const unsigned short*)xp + (size_t)r * 1024 + t * 4);
    v0 = b2f(raw.x); v1 = b2f(raw.y); v2 = b2f(raw.z); v3 = b2f(raw.w);
  } else {
    const float4 raw = *(const float4*)((const float*)xp + (size_t)r * 1024 + t * 4);
    v0 = raw.x; v1 = raw.y; v2 = raw.z; v3 = raw.w;
  }
  float s  = v0 + v1 + v2 + v3;
  float s2 = v0 * v0 + v1 * v1 + v2 * v2 + v3 * v3;
#pragma unroll
  for (int off = 32; off > 0; off >>= 1) {
    s  += __shfl_down(s, off);
    s2 += __shfl_down(s2, off);
  }
  __shared__ float red[8];
  const int w = t >> 6, lane = t & 63;
  if (lane == 0) { red[w] = s; red[4 + w] = s2; }
  __syncthreads();
  if (t == 0) {
    float ts = red[0] + red[1] + red[2] + red[3];
    float t2 = red[4] + red[5] + red[6] + red[7];
    float mu = ts * (1.0f / 1024.0f);
    float var = t2 * (1.0f / 1024.0f) - mu * mu;
    red[0] = mu;
    red[1] = rsqrtf(var + 1e-5f);
  }
  __syncthreads();
  const float mu = red[0], rs = red[1];
  const float4 graw = *(const float4*)(g + t * 4);
  const float4 braw = *(const float4*)(bta + t * 4);
  ushort4 o;
  o.x = f2b((v0 - mu) * rs * graw.x + braw.x);
  o.y = f2b((v1 - mu) * rs * graw.y + braw.y);
  o.z = f2b((v2 - mu) * rs * graw.z + braw.z);
  o.w = f2b((v3 - mu) * rs * graw.w + braw.w);
  *(ushort4*)(out + (size_t)r * 1024 + t * 4) = o;
}

// ---------- MFMA GEMM: C[M,N] = A[M,K] @ Bt[N,K]^T (+bias)(+gelu)(+res) ----------
// Distance-2 pipeline (3 LDS bufs, counted vmcnt across raw barriers) + T2 swizzle:
// 16B chunk within each 64B row is XOR'd with (row>>1)&3. LDS dest stays LINEAR
// (global_load_lds constraint, rule 21) — the permutation is applied to the GLOBAL
// source offset at stage time and to the read offset; both are loop-invariant.
__global__ __launch_bounds__(256, 2) void gemm_bt(const unsigned short* __restrict__ A,
                                                  const unsigned short* __restrict__ Bt,
                                                  const float* __restrict__ bias,
                                                  const void* __restrict__ res, int res_bf16,
                                                  void* __restrict__ Cout,
                                                  int M, int N, int K, int act, int out_bf16,
                                                  int swap_xy) {
  __shared__ __align__(16) unsigned short As[3][128 * 32];
  __shared__ __align__(16) unsigned short Bs[3][128 * 32];
  const int t = threadIdx.x;
  const int lane = t & 63, w = t >> 6;
  const int wr = (w >> 1) * 64, wc = (w & 1) * 64;
  const int lr = lane & 15, lq = lane >> 4;
  const int mb = swap_xy ? blockIdx.x : blockIdx.y;
  const int nb = swap_xy ? blockIdx.y : blockIdx.x;
  const int m0 = mb * 128, n0 = nb * 128;

  // staging: chunk c -> LDS linear (row=c>>2, chunk=c&3); source chunk = (c&3)^((row>>1)&3)
  const int c0 = t, c1 = t + 256;
  const int r0 = c0 >> 2, o0 = (((c0 & 3) ^ ((c0 >> 3) & 3)) << 3);
  const int r1 = c1 >> 2, o1 = (((c1 & 3) ^ ((c1 >> 3) & 3)) << 3);
  const unsigned short* Ag0 = A  + (size_t)(m0 + r0) * K + o0;
  const unsigned short* Ag1 = A  + (size_t)(m0 + r1) * K + o1;
  const unsigned short* Bg0 = Bt + (size_t)(n0 + r0) * K + o0;
  const unsigned short* Bg1 = Bt + (size_t)(n0 + r1) * K + o1;

  // read-side swizzled chunk offset (row = ..+lr => s(row) = (lr>>1)&3, invariant)
  const int ra = ((lq ^ ((lr >> 1) & 3)) << 3);

  v4f acc[4][4];
#pragma unroll
  for (int mi = 0; mi < 4; ++mi)
#pragma unroll
    for (int ni = 0; ni < 4; ++ni)
      acc[mi][ni] = (v4f){0.f, 0.f, 0.f, 0.f};

  const int nt = K >> 5;
  // prologue: stage tiles 0 and 1
  g2l16(Ag0, &As[0][c0 * 8]); g2l16(Bg0, &Bs[0][c0 * 8]);
  g2l16(Ag1, &As[0][c1 * 8]); g2l16(Bg1, &Bs[0][c1 * 8]);
  if (nt > 1) {
    g2l16(Ag0 + 32, &As[1][c0 * 8]); g2l16(Bg0 + 32, &Bs[1][c0 * 8]);
    g2l16(Ag1 + 32, &As[1][c1 * 8]); g2l16(Bg1 + 32, &Bs[1][c1 * 8]);
  }

  int bi = 0;
  for (int tt = 0; tt < nt; ++tt) {
    const int pf = tt + 2;
    if (pf < nt) {
      const int ko = pf << 5;
      const int pb = pf % 3;
      g2l16(Ag0 + ko, &As[pb][c0 * 8]); g2l16(Bg0 + ko, &Bs[pb][c0 * 8]);
      g2l16(Ag1 + ko, &As[pb][c1 * 8]); g2l16(Bg1 + ko, &Bs[pb][c1 * 8]);
      asm volatile("s_waitcnt vmcnt(8)" ::: "memory");
    } else if (tt + 1 < nt) {
      asm volatile("s_waitcnt vmcnt(4)" ::: "memory");
    } else {
      asm volatile("s_waitcnt vmcnt(0)" ::: "memory");
    }
    __builtin_amdgcn_s_barrier();
    asm volatile("" ::: "memory");

    v8bf af[4], bfr[4];
#pragma unroll
    for (int i = 0; i < 4; ++i) {
      af[i]  = *(const v8bf*)(&As[bi][(wr + i * 16 + lr) * 32 + ra]);
      bfr[i] = *(const v8bf*)(&Bs[bi][(wc + i * 16 + lr) * 32 + ra]);
    }
#pragma unroll
    for (int mi = 0; mi < 4; ++mi)
#pragma unroll
      for (int ni = 0; ni < 4; ++ni)
        acc[mi][ni] = __builtin_amdgcn_mfma_f32_16x16x32_bf16(af[mi], bfr[ni], acc[mi][ni], 0, 0, 0);

    asm volatile("" ::: "memory");
    __builtin_amdgcn_s_barrier();
    bi = (bi == 2) ? 0 : bi + 1;
  }

#pragma unroll
  for (int mi = 0; mi < 4; ++mi) {
#pragma unroll
    for (int ni = 0; ni < 4; ++ni) {
      const int col = n0 + wc + ni * 16 + lr;
      const float bv = bias ? bias[col] : 0.0f;
#pragma unroll
      for (int r = 0; r < 4; ++r) {
        const int row = m0 + wr + mi * 16 + lq * 4 + r;
        float v = acc[mi][ni][r] + bv;
        if (act) v = gelu_fast(v);
        if (res) {
          v += res_bf16 ? b2f(((const unsigned short*)res)[(size_t)row * N + col])
                        : ((const float*)res)[(size_t)row * N + col];
        }
        if (out_bf16)
          ((unsigned short*)Cout)[(size_t)row * N + col] = f2b(v);
        else
          ((float*)Cout)[(size_t)row * N + col] = v;
      }
    }
  }
}

// ---------- V restage: qkv[token][3072] v-part -> Vt[(b*16+h)*64+d][2048 tokens] ----------
__global__ __launch_bounds__(256) void vt_k(const unsigned short* __restrict__ qkv,
                                            unsigned short* __restrict__ Vt) {
  const int t = threadIdx.x;
  const int n = blockIdx.x * 256 + t, h = blockIdx.y, b = blockIdx.z;
  const size_t src = (size_t)(b * 2048 + n) * 3072 + 2048 + h * 64;
  unsigned short v[64];
#pragma unroll
  for (int j = 0; j < 8; ++j)
    *(uint4*)(v + j * 8) = *(const uint4*)(qkv + src + j * 8);
  const size_t dstbase = ((size_t)(b * 16 + h) * 64) * 2048 + n;
#pragma unroll
  for (int d = 0; d < 64; ++d)
    Vt[dstbase + (size_t)d * 2048] = v[d];
}

// ---------- MFMA flash attention ----------
// K/V per head (256 KB each) is L2-resident (XCD pinned via h%8 swizzle; measured
// HBM 4.4%). Per m169/Common-mistake-#7: drop the K/V LDS staging AND both per-kt
// barriers — read K/V fragments b128 directly from L2, waves free-run. Only Ps
// (per-warp, barrier-free) stays in LDS -> 19.5 KB, 4 blocks/CU of TLP to cover
// the softmax-VALU critical path. bv loads issue before softmax (latency hides
// under ~700cy of exp/pack).
__global__ __launch_bounds__(256, 4) void attn_mfma(const unsigned short* __restrict__ qkv,
                                                    const unsigned short* __restrict__ Vt,
                                                    unsigned short* __restrict__ out) {
  __shared__ __align__(16) unsigned short Ps[4][32 * 76];
  const int t = threadIdx.x;
  const int lane = t & 63, w = t >> 6;
  const int lr = lane & 15, lq = lane >> 4;
  const int h = blockIdx.x, b = blockIdx.z;
  const int q0 = blockIdx.y * 128 + w * 32;

  v8bf aq[2][2];
#pragma unroll
  for (int mi = 0; mi < 2; ++mi)
#pragma unroll
    for (int kq = 0; kq < 2; ++kq)
      aq[mi][kq] = *(const v8bf*)(qkv + (size_t)(b * 2048 + q0 + mi * 16 + lr) * 3072
                                  + h * 64 + kq * 32 + lq * 8);

  v4f acc_o[2][4];
  float lsum[2][4];
#pragma unroll
  for (int mi = 0; mi < 2; ++mi)
#pragma unroll
    for (int di = 0; di < 4; ++di)
      acc_o[mi][di] = (v4f){0.f, 0.f, 0.f, 0.f};
#pragma unroll
  for (int mi = 0; mi < 2; ++mi)
#pragma unroll
    for (int r = 0; r < 4; ++r)
      lsum[mi][r] = 0.0f;

  // per-lane K/V base pointers
  const unsigned short* Kb = qkv + (size_t)b * 2048 * 3072 + 1024 + h * 64 + lq * 8;
  const unsigned short* Vb = Vt + ((size_t)(b * 16 + h) * 64 + lr) * 2048 + lq * 8;

  for (int kt = 0; kt < 32; ++kt) {
    const int kt0 = kt * 64;

    // ---- QK^T: K fragments straight from L2 ----
    v4f s_acc[2][4];
#pragma unroll
    for (int mi = 0; mi < 2; ++mi)
#pragma unroll
      for (int ni = 0; ni < 4; ++ni)
        s_acc[mi][ni] = (v4f){0.f, 0.f, 0.f, 0.f};
#pragma unroll
    for (int kq = 0; kq < 2; ++kq) {
      v8bf bk[4];
#pragma unroll
      for (int ni = 0; ni < 4; ++ni)
        bk[ni] = *(const v8bf*)(Kb + (size_t)(kt0 + ni * 16 + lr) * 3072 + kq * 32);
      __builtin_amdgcn_s_setprio(1);
#pragma unroll
      for (int mi = 0; mi < 2; ++mi)
#pragma unroll
        for (int ni = 0; ni < 4; ++ni)
          s_acc[mi][ni] = __builtin_amdgcn_mfma_f32_16x16x32_bf16(aq[mi][kq], bk[ni], s_acc[mi][ni], 0, 0, 0);
      __builtin_amdgcn_s_setprio(0);
    }

    // ---- issue V loads now; latency hides under softmax VALU ----
    v8bf bv[2][4];
#pragma unroll
    for (int ks = 0; ks < 2; ++ks)
#pragma unroll
      for (int di = 0; di < 4; ++di)
        bv[ks][di] = *(const v8bf*)(Vb + (size_t)(di * 16) * 2048 + kt0 + ks * 32);

    // ---- softmax (no running max needed: |s*0.125| small) ----
#pragma unroll
    for (int mi = 0; mi < 2; ++mi)
#pragma unroll
      for (int ni = 0; ni < 4; ++ni)
#pragma unroll
        for (int r = 0; r < 4; ++r) {
          const float p = __expf(s_acc[mi][ni][r] * 0.125f);
          const unsigned short pb = f2b_trunc(p);
          lsum[mi][r] += b2f(pb);
          Ps[w][(mi * 16 + lq * 4 + r) * 76 + ni * 16 + lr] = pb;
        }

    // ---- P @ V ----
#pragma unroll
    for (int ks = 0; ks < 2; ++ks) {
      v8bf ap[2];
#pragma unroll
      for (int mi = 0; mi < 2; ++mi) {
        const unsigned short* base = Ps[w] + (mi * 16 + lr) * 76 + ks * 32 + lq * 8;
        const v4bf lo = *(const v4bf*)(base);
        const v4bf hi = *(const v4bf*)(base + 4);
        ap[mi] = __builtin_shufflevector(lo, hi, 0, 1, 2, 3, 4, 5, 6, 7);
      }
      __builtin_amdgcn_s_setprio(1);
#pragma unroll
      for (int mi = 0; mi < 2; ++mi)
#pragma unroll
        for (int di = 0; di < 4; ++di)
          acc_o[mi][di] = __builtin_amdgcn_mfma_f32_16x16x32_bf16(ap[mi], bv[ks][di], acc_o[mi][di], 0, 0, 0);
      __builtin_amdgcn_s_setprio(0);
    }
  }

#pragma unroll
  for (int mi = 0; mi < 2; ++mi)
#pragma unroll
    for (int r = 0; r < 4; ++r) {
      float v = lsum[mi][r];
      v += __shfl_xor(v, 1);
      v += __shfl_xor(v, 2);
      v += __shfl_xor(v, 4);
      v += __shfl_xor(v, 8);
      lsum[mi][r] = 1.0f / v;
    }

#pragma unroll
  for (int mi = 0; mi < 2; ++mi)
#pragma unroll
    for (int di = 0; di < 4; ++di)
#pragma unroll
      for (int r = 0; r < 4; ++r)
        out[(size_t)(b * 2048 + q0 + mi * 16 + lq * 4 + r) * 1024 + h * 64 + di * 16 + lr] =
            f2b(acc_o[mi][di][r] * lsum[mi][r]);
}

// ---------- launch ----------
// ws layout (112 MiB): T_a [0,8M) wt_qkv->wt_w1; T_b [8,16M) wt_proj->wt_w2;
// x2 bf16 [16,32M); Vt [32,48M); H [48,64M) h->o; qkv [64,112M);
// h3 [48,112M) overlays dead H+qkv; h2 bf16 in d_out scratch.
extern "C" void kernel_launch(void* const* d_in, const int* in_sizes, int n_in,
                              void* d_out, int out_size, void* d_ws, size_t ws_size,
                              hipStream_t stream) {
  (void)in_sizes; (void)n_in; (void)out_size; (void)ws_size;
  const float* x      = (const float*)d_in[0];
  const float* w_qkv  = (const float*)d_in[1];
  const float* w_proj = (const float*)d_in[2];
  const float* b_proj = (const float*)d_in[3];
  const float* ln1_g  = (const float*)d_in[4];
  const float* ln1_b  = (const float*)d_in[5];
  const float* w1     = (const float*)d_in[6];
  const float* b1     = (const float*)d_in[7];
  const float* w2     = (const float*)d_in[8];
  const float* b2     = (const float*)d_in[9];
  const float* ln2_g  = (const float*)d_in[10];
  const float* ln2_b  = (const float*)d_in[11];
  float* out = (float*)d_out;

  char* ws = (char*)d_ws;
  unsigned short* T_a   = (unsigned short*)(ws);
  unsigned short* T_b   = (unsigned short*)(ws + 8388608);
  unsigned short* x2buf = (unsigned short*)(ws + 16777216);   // bf16 [8192,1024]
  unsigned short* Vtbuf = (unsigned short*)(ws + 33554432);
  unsigned short* Hbuf  = (unsigned short*)(ws + 50331648);
  unsigned short* qkvb  = (unsigned short*)(ws + 67108864);
  unsigned short* h3buf = (unsigned short*)(ws + 50331648);
  unsigned short* h2buf = (unsigned short*)d_out;

  const dim3 tb(32, 8);
  transpose_k<<<dim3(96, 32),  tb, 0, stream>>>(w_qkv,  T_a, 1024, 3072);
  transpose_k<<<dim3(32, 32),  tb, 0, stream>>>(w_proj, T_b, 1024, 1024);
  // h = LN1(x)
  ln_kernel<<<8192, 256, 0, stream>>>(x, 0, ln1_g, ln1_b, Hbuf);
  // qkv = h @ w_qkv
  gemm_bt<<<dim3(24, 64), 256, 0, stream>>>(Hbuf, T_a, nullptr, nullptr, 0, qkvb, 8192, 3072, 1024, 0, 1, 0);
  transpose_k<<<dim3(128, 32), tb, 0, stream>>>(w1, T_a, 1024, 4096);
  // attention
  vt_k<<<dim3(8, 16, 4), 256, 0, stream>>>(qkvb, Vtbuf);
  attn_mfma<<<dim3(16, 16, 4), 256, 0, stream>>>(qkvb, Vtbuf, Hbuf);
  // x2 = o @ w_proj + b_proj + x  (bf16 out, XCD row-sharing swizzle)
  gemm_bt<<<dim3(64, 8), 256, 0, stream>>>(Hbuf, T_b, b_proj, x, 0, x2buf, 8192, 1024, 1024, 0, 1, 1);
  transpose_k<<<dim3(32, 128), tb, 0, stream>>>(w2, T_b, 4096, 1024);
  // h2 = LN2(x2)
  ln_kernel<<<8192, 256, 0, stream>>>(x2buf, 1, ln2_g, ln2_b, h2buf);
  // h3 = gelu(h2 @ w1 + b1)
  gemm_bt<<<dim3(32, 64), 256, 0, stream>>>(h2buf, T_a, b1, nullptr, 0, h3buf, 8192, 4096, 1024, 1, 1, 0);
  // out = h3 @ w2 + b2 + x2  (fp32 out, swizzle)
  gemm_bt<<<dim3(64, 8), 256, 0, stream>>>(h3buf, T_b, b2, x2buf, 1, out, 8192, 1024, 4096, 0, 0, 1);
}

// Round 3
// 672.354 us; speedup vs baseline: 1.1181x; 1.1181x over previous
//
#include <hip/hip_runtime.h>
#include <cstdint>
#include <cstddef>

// ---------- types / helpers ----------
typedef float  v4f  __attribute__((ext_vector_type(4)));
typedef __bf16 v8bf __attribute__((ext_vector_type(8)));
typedef __bf16 v4bf __attribute__((ext_vector_type(4)));

__device__ __forceinline__ float b2f(unsigned short u) {
  union { unsigned int i; float f; } cv; cv.i = ((unsigned int)u) << 16; return cv.f;
}
__device__ __forceinline__ unsigned short f2b(float f) {
  union { float f; unsigned int i; } cv; cv.f = f;
  unsigned int i = cv.i;
  i += 0x7fffu + ((i >> 16) & 1u);      // round-to-nearest-even
  return (unsigned short)(i >> 16);
}
__device__ __forceinline__ unsigned short f2b_trunc(float f) {
  union { float f; unsigned int i; } cv; cv.f = f;
  return (unsigned short)(cv.i >> 16);  // truncate (cheap); P only
}
// tanh-form GELU: x*sigmoid(1.59577*(x+0.044715x^3)); |err vs erf-GELU| <= ~3e-4.
__device__ __forceinline__ float gelu_fast(float x) {
  const float u = x * (1.5957691216f + 0.07135481627f * x * x);
  return x * (1.0f / (1.0f + __expf(-u)));
}
__device__ __forceinline__ void g2l16(const unsigned short* g, unsigned short* l) {
  __builtin_amdgcn_global_load_lds(
      (const __attribute__((address_space(1))) void*)g,
      (__attribute__((address_space(3))) void*)l,
      16, 0, 0);
}

// ---------- transpose + fp32->bf16 convert: in[R,C] f32 -> out[C,R] bf16 ----------
__global__ __launch_bounds__(256) void transpose_k(const float* __restrict__ in,
                                                   unsigned short* __restrict__ out,
                                                   int R, int C) {
  __shared__ float tile[32][33];
  const int tx = threadIdx.x, ty = threadIdx.y;
  const int r0 = blockIdx.y * 32, c0 = blockIdx.x * 32;
#pragma unroll
  for (int j = 0; j < 4; ++j)
    tile[ty + 8 * j][tx] = in[(size_t)(r0 + ty + 8 * j) * C + c0 + tx];
  __syncthreads();
#pragma unroll
  for (int j = 0; j < 4; ++j)
    out[(size_t)(c0 + ty + 8 * j) * R + r0 + tx] = f2b(tile[tx][ty + 8 * j]);
}

// ---------- layernorm over DIM=1024 (fp32 or bf16 in, bf16 out) ----------
__global__ __launch_bounds__(256) void ln_kernel(const void* __restrict__ xp, int in_bf16,
                                                 const float* __restrict__ g,
                                                 const float* __restrict__ bta,
                                                 unsigned short* __restrict__ out) {
  const int r = blockIdx.x, t = threadIdx.x;
  float v0, v1, v2, v3;
  if (in_bf16) {
    const ushort4 raw = *(const ushort4*)((const unsigned short*)xp + (size_t)r * 1024 + t * 4);
    v0 = b2f(raw.x); v1 = b2f(raw.y); v2 = b2f(raw.z); v3 = b2f(raw.w);
  } else {
    const float4 raw = *(const float4*)((const float*)xp + (size_t)r * 1024 + t * 4);
    v0 = raw.x; v1 = raw.y; v2 = raw.z; v3 = raw.w;
  }
  float s  = v0 + v1 + v2 + v3;
  float s2 = v0 * v0 + v1 * v1 + v2 * v2 + v3 * v3;
#pragma unroll
  for (int off = 32; off > 0; off >>= 1) {
    s  += __shfl_down(s, off);
    s2 += __shfl_down(s2, off);
  }
  __shared__ float red[8];
  const int w = t >> 6, lane = t & 63;
  if (lane == 0) { red[w] = s; red[4 + w] = s2; }
  __syncthreads();
  if (t == 0) {
    float ts = red[0] + red[1] + red[2] + red[3];
    float t2 = red[4] + red[5] + red[6] + red[7];
    float mu = ts * (1.0f / 1024.0f);
    float var = t2 * (1.0f / 1024.0f) - mu * mu;
    red[0] = mu;
    red[1] = rsqrtf(var + 1e-5f);
  }
  __syncthreads();
  const float mu = red[0], rs = red[1];
  const float4 graw = *(const float4*)(g + t * 4);
  const float4 braw = *(const float4*)(bta + t * 4);
  ushort4 o;
  o.x = f2b((v0 - mu) * rs * graw.x + braw.x);
  o.y = f2b((v1 - mu) * rs * graw.y + braw.y);
  o.z = f2b((v2 - mu) * rs * graw.z + braw.z);
  o.w = f2b((v3 - mu) * rs * graw.w + braw.w);
  *(ushort4*)(out + (size_t)r * 1024 + t * 4) = o;
}

// ---------- MFMA GEMM: C[M,N] = A[M,K] @ Bt[N,K]^T (+bias)(+gelu)(+res) ----------
// 256x128 block tile, 4 waves of 128x64 each. Per K=32 step per wave: 32 MFMA
// (154cy matrix) vs 12 ds_read_b128 (144cy LDS) — matrix-balanced (the old 128²
// tile was 16 MFMA vs 8 reads + 45 VALU = overhead-bound at ~500 TF).
// Distance-2 pipeline: 3 LDS bufs, counted s_waitcnt vmcnt(12) across raw
// barriers keeps 2 tiles (12 loads/wave) in flight. Chunk-XOR swizzle (T2,
// rule 21): LDS dest linear (global_load_lds), source chunk pre-XOR'd with
// (row>>1)&3, read applies the same XOR.
__global__ __launch_bounds__(256, 2) void gemm_bt(const unsigned short* __restrict__ A,
                                                  const unsigned short* __restrict__ Bt,
                                                  const float* __restrict__ bias,
                                                  const void* __restrict__ res, int res_bf16,
                                                  void* __restrict__ Cout,
                                                  int M, int N, int K, int act, int out_bf16,
                                                  int swap_xy) {
  __shared__ __align__(16) unsigned short As[3][256 * 32];
  __shared__ __align__(16) unsigned short Bs[3][128 * 32];
  const int t = threadIdx.x;
  const int lane = t & 63, w = t >> 6;
  const int wr = (w >> 1) * 128, wc = (w & 1) * 64;
  const int lr = lane & 15, lq = lane >> 4;
  const int mb = swap_xy ? blockIdx.x : blockIdx.y;
  const int nb = swap_xy ? blockIdx.y : blockIdx.x;
  const int m0 = mb * 256, n0 = nb * 128;

  // staging: chunk c -> LDS linear (row=c>>2, chunk=c&3); source chunk=(c&3)^((row>>1)&3)
  const unsigned short* Ag0;
  const unsigned short* Ag1;
  const unsigned short* Ag2;
  const unsigned short* Ag3;
  const unsigned short* Bg0;
  const unsigned short* Bg1;
  {
    const int cA0 = t,        rA0 = cA0 >> 2, oA0 = (((cA0 & 3) ^ ((cA0 >> 3) & 3)) << 3);
    const int cA1 = t + 256,  rA1 = cA1 >> 2, oA1 = (((cA1 & 3) ^ ((cA1 >> 3) & 3)) << 3);
    const int cA2 = t + 512,  rA2 = cA2 >> 2, oA2 = (((cA2 & 3) ^ ((cA2 >> 3) & 3)) << 3);
    const int cA3 = t + 768,  rA3 = cA3 >> 2, oA3 = (((cA3 & 3) ^ ((cA3 >> 3) & 3)) << 3);
    Ag0 = A + (size_t)(m0 + rA0) * K + oA0;
    Ag1 = A + (size_t)(m0 + rA1) * K + oA1;
    Ag2 = A + (size_t)(m0 + rA2) * K + oA2;
    Ag3 = A + (size_t)(m0 + rA3) * K + oA3;
    Bg0 = Bt + (size_t)(n0 + rA0) * K + oA0;
    Bg1 = Bt + (size_t)(n0 + rA1) * K + oA1;
  }
  // read-side swizzled chunk offset ((row>>1)&3 == (lr>>1)&3 since wr/wc, mi*16 are mult of 8 rows)
  const int ra = ((lq ^ ((lr >> 1) & 3)) << 3);

  v4f acc[8][4];
#pragma unroll
  for (int mi = 0; mi < 8; ++mi)
#pragma unroll
    for (int ni = 0; ni < 4; ++ni)
      acc[mi][ni] = (v4f){0.f, 0.f, 0.f, 0.f};

#define STAGE(buf, ko)                                  \
  do {                                                  \
    g2l16(Ag0 + (ko), &As[buf][(t)*8]);                 \
    g2l16(Ag1 + (ko), &As[buf][(t + 256) * 8]);         \
    g2l16(Ag2 + (ko), &As[buf][(t + 512) * 8]);         \
    g2l16(Ag3 + (ko), &As[buf][(t + 768) * 8]);         \
    g2l16(Bg0 + (ko), &Bs[buf][(t)*8]);                 \
    g2l16(Bg1 + (ko), &Bs[buf][(t + 256) * 8]);         \
  } while (0)

  const int nt = K >> 5;
  STAGE(0, 0);
  STAGE(1, 32);

  int bi = 0;
  for (int tt = 0; tt < nt; ++tt) {
    const int pf = tt + 2;
    if (pf < nt) {
      STAGE(pf % 3, pf << 5);
      // tiles tt+1, tt+2 stay in flight (12 loads); tile tt guaranteed landed
      asm volatile("s_waitcnt vmcnt(12)" ::: "memory");
    } else if (tt + 1 < nt) {
      asm volatile("s_waitcnt vmcnt(6)" ::: "memory");
    } else {
      asm volatile("s_waitcnt vmcnt(0)" ::: "memory");
    }
    __builtin_amdgcn_s_barrier();
    asm volatile("" ::: "memory");

    v8bf bfr[4];
#pragma unroll
    for (int i = 0; i < 4; ++i)
      bfr[i] = *(const v8bf*)(&Bs[bi][(wc + i * 16 + lr) * 32 + ra]);
#pragma unroll
    for (int mi = 0; mi < 8; ++mi) {
      const v8bf af = *(const v8bf*)(&As[bi][(wr + mi * 16 + lr) * 32 + ra]);
#pragma unroll
      for (int ni = 0; ni < 4; ++ni)
        acc[mi][ni] = __builtin_amdgcn_mfma_f32_16x16x32_bf16(af, bfr[ni], acc[mi][ni], 0, 0, 0);
    }

    asm volatile("" ::: "memory");
    __builtin_amdgcn_s_barrier();
    bi = (bi == 2) ? 0 : bi + 1;
  }
#undef STAGE

#pragma unroll
  for (int mi = 0; mi < 8; ++mi) {
#pragma unroll
    for (int ni = 0; ni < 4; ++ni) {
      const int col = n0 + wc + ni * 16 + lr;
      const float bv = bias ? bias[col] : 0.0f;
#pragma unroll
      for (int r = 0; r < 4; ++r) {
        const int row = m0 + wr + mi * 16 + lq * 4 + r;
        float v = acc[mi][ni][r] + bv;
        if (act) v = gelu_fast(v);
        if (res) {
          v += res_bf16 ? b2f(((const unsigned short*)res)[(size_t)row * N + col])
                        : ((const float*)res)[(size_t)row * N + col];
        }
        if (out_bf16)
          ((unsigned short*)Cout)[(size_t)row * N + col] = f2b(v);
        else
          ((float*)Cout)[(size_t)row * N + col] = v;
      }
    }
  }
}

// ---------- V restage: qkv[token][3072] v-part -> Vt[(b*16+h)*64+d][2048 tokens] ----------
__global__ __launch_bounds__(256) void vt_k(const unsigned short* __restrict__ qkv,
                                            unsigned short* __restrict__ Vt) {
  const int t = threadIdx.x;
  const int n = blockIdx.x * 256 + t, h = blockIdx.y, b = blockIdx.z;
  const size_t src = (size_t)(b * 2048 + n) * 3072 + 2048 + h * 64;
  unsigned short v[64];
#pragma unroll
  for (int j = 0; j < 8; ++j)
    *(uint4*)(v + j * 8) = *(const uint4*)(qkv + src + j * 8);
  const size_t dstbase = ((size_t)(b * 16 + h) * 64) * 2048 + n;
#pragma unroll
  for (int d = 0; d < 64; ++d)
    Vt[dstbase + (size_t)d * 2048] = v[d];
}

// ---------- MFMA flash attention (round-1 verified structure: LDS-staged K/V,
// T14 async reg-stage split, setprio around MFMA clusters) ----------
__global__ __launch_bounds__(256, 2) void attn_mfma(const unsigned short* __restrict__ qkv,
                                                    const unsigned short* __restrict__ Vt,
                                                    unsigned short* __restrict__ out) {
  __shared__ __align__(16) unsigned short Ks[64 * 80];
  __shared__ __align__(16) unsigned short Vs[64 * 80];
  __shared__ __align__(16) unsigned short Ps[4][32 * 76];
  const int t = threadIdx.x;
  const int lane = t & 63, w = t >> 6;
  const int lr = lane & 15, lq = lane >> 4;
  const int h = blockIdx.x, b = blockIdx.z;
  const int q0 = blockIdx.y * 128 + w * 32;

  v8bf aq[2][2];
#pragma unroll
  for (int mi = 0; mi < 2; ++mi)
#pragma unroll
    for (int kq = 0; kq < 2; ++kq)
      aq[mi][kq] = *(const v8bf*)(qkv + (size_t)(b * 2048 + q0 + mi * 16 + lr) * 3072
                                  + h * 64 + kq * 32 + lq * 8);

  v4f acc_o[2][4];
  float lsum[2][4];
#pragma unroll
  for (int mi = 0; mi < 2; ++mi)
#pragma unroll
    for (int di = 0; di < 4; ++di)
      acc_o[mi][di] = (v4f){0.f, 0.f, 0.f, 0.f};
#pragma unroll
  for (int mi = 0; mi < 2; ++mi)
#pragma unroll
    for (int r = 0; r < 4; ++r)
      lsum[mi][r] = 0.0f;

  // per-thread K/V staging addresses (2 chunks of 16B each)
  const int sc0 = t, sc1 = t + 256;
  const int kr0 = sc0 >> 3, ko0 = (sc0 & 7) * 8;
  const int kr1 = sc1 >> 3, ko1 = (sc1 & 7) * 8;
  const unsigned short* Kg0 = qkv + (size_t)(b * 2048 + kr0) * 3072 + 1024 + h * 64 + ko0;
  const unsigned short* Kg1 = qkv + (size_t)(b * 2048 + kr1) * 3072 + 1024 + h * 64 + ko1;
  const unsigned short* Vg0 = Vt + ((size_t)(b * 16 + h) * 64 + kr0) * 2048 + ko0;
  const unsigned short* Vg1 = Vt + ((size_t)(b * 16 + h) * 64 + kr1) * 2048 + ko1;

  // prologue: tile 0 into LDS
  uint4 kreg0 = *(const uint4*)(Kg0);
  uint4 kreg1 = *(const uint4*)(Kg1);
  uint4 vreg0 = *(const uint4*)(Vg0);
  uint4 vreg1 = *(const uint4*)(Vg1);
  *(uint4*)(Ks + kr0 * 80 + ko0) = kreg0;
  *(uint4*)(Ks + kr1 * 80 + ko1) = kreg1;
  *(uint4*)(Vs + kr0 * 80 + ko0) = vreg0;
  *(uint4*)(Vs + kr1 * 80 + ko1) = vreg1;
  __syncthreads();

  for (int kt = 0; kt < 32; ++kt) {
    // issue next tile's global loads early; latency hides under compute
    if (kt < 31) {
      const size_t kn = (size_t)(kt + 1) * 64;
      kreg0 = *(const uint4*)(Kg0 + kn * 3072);
      kreg1 = *(const uint4*)(Kg1 + kn * 3072);
      vreg0 = *(const uint4*)(Vg0 + kn);
      vreg1 = *(const uint4*)(Vg1 + kn);
    }

    v4f s_acc[2][4];
#pragma unroll
    for (int mi = 0; mi < 2; ++mi)
#pragma unroll
      for (int ni = 0; ni < 4; ++ni)
        s_acc[mi][ni] = (v4f){0.f, 0.f, 0.f, 0.f};
#pragma unroll
    for (int kq = 0; kq < 2; ++kq) {
      v8bf bk[4];
#pragma unroll
      for (int ni = 0; ni < 4; ++ni)
        bk[ni] = *(const v8bf*)(Ks + (ni * 16 + lr) * 80 + kq * 32 + lq * 8);
      __builtin_amdgcn_s_setprio(1);
#pragma unroll
      for (int mi = 0; mi < 2; ++mi)
#pragma unroll
        for (int ni = 0; ni < 4; ++ni)
          s_acc[mi][ni] = __builtin_amdgcn_mfma_f32_16x16x32_bf16(aq[mi][kq], bk[ni], s_acc[mi][ni], 0, 0, 0);
      __builtin_amdgcn_s_setprio(0);
    }

#pragma unroll
    for (int mi = 0; mi < 2; ++mi)
#pragma unroll
      for (int ni = 0; ni < 4; ++ni)
#pragma unroll
        for (int r = 0; r < 4; ++r) {
          const float p = __expf(s_acc[mi][ni][r] * 0.125f);
          const unsigned short pb = f2b_trunc(p);
          lsum[mi][r] += b2f(pb);
          Ps[w][(mi * 16 + lq * 4 + r) * 76 + ni * 16 + lr] = pb;
        }

#pragma unroll
    for (int ks = 0; ks < 2; ++ks) {
      v8bf ap[2], bv[4];
#pragma unroll
      for (int mi = 0; mi < 2; ++mi) {
        const unsigned short* base = Ps[w] + (mi * 16 + lr) * 76 + ks * 32 + lq * 8;
        const v4bf lo = *(const v4bf*)(base);
        const v4bf hi = *(const v4bf*)(base + 4);
        ap[mi] = __builtin_shufflevector(lo, hi, 0, 1, 2, 3, 4, 5, 6, 7);
      }
#pragma unroll
      for (int di = 0; di < 4; ++di)
        bv[di] = *(const v8bf*)(Vs + (di * 16 + lr) * 80 + ks * 32 + lq * 8);
      __builtin_amdgcn_s_setprio(1);
#pragma unroll
      for (int mi = 0; mi < 2; ++mi)
#pragma unroll
        for (int di = 0; di < 4; ++di)
          acc_o[mi][di] = __builtin_amdgcn_mfma_f32_16x16x32_bf16(ap[mi], bv[ks == 0 ? di : di], acc_o[mi][di], 0, 0, 0);
      __builtin_amdgcn_s_setprio(0);
    }

    __syncthreads();            // all waves done reading Ks/Vs
    if (kt < 31) {
      *(uint4*)(Ks + kr0 * 80 + ko0) = kreg0;
      *(uint4*)(Ks + kr1 * 80 + ko1) = kreg1;
      *(uint4*)(Vs + kr0 * 80 + ko0) = vreg0;
      *(uint4*)(Vs + kr1 * 80 + ko1) = vreg1;
    }
    __syncthreads();            // next tile visible
  }

#pragma unroll
  for (int mi = 0; mi < 2; ++mi)
#pragma unroll
    for (int r = 0; r < 4; ++r) {
      float v = lsum[mi][r];
      v += __shfl_xor(v, 1);
      v += __shfl_xor(v, 2);
      v += __shfl_xor(v, 4);
      v += __shfl_xor(v, 8);
      lsum[mi][r] = 1.0f / v;
    }

#pragma unroll
  for (int mi = 0; mi < 2; ++mi)
#pragma unroll
    for (int di = 0; di < 4; ++di)
#pragma unroll
      for (int r = 0; r < 4; ++r)
        out[(size_t)(b * 2048 + q0 + mi * 16 + lq * 4 + r) * 1024 + h * 64 + di * 16 + lr] =
            f2b(acc_o[mi][di][r] * lsum[mi][r]);
}

// ---------- launch ----------
// ws layout (112 MiB): T_a [0,8M) wt_qkv->wt_w1; T_b [8,16M) wt_proj->wt_w2;
// x2 bf16 [16,32M); Vt [32,48M); H [48,64M) h->o; qkv [64,112M);
// h3 [48,112M) overlays dead H+qkv; h2 bf16 in d_out scratch.
extern "C" void kernel_launch(void* const* d_in, const int* in_sizes, int n_in,
                              void* d_out, int out_size, void* d_ws, size_t ws_size,
                              hipStream_t stream) {
  (void)in_sizes; (void)n_in; (void)out_size; (void)ws_size;
  const float* x      = (const float*)d_in[0];
  const float* w_qkv  = (const float*)d_in[1];
  const float* w_proj = (const float*)d_in[2];
  const float* b_proj = (const float*)d_in[3];
  const float* ln1_g  = (const float*)d_in[4];
  const float* ln1_b  = (const float*)d_in[5];
  const float* w1     = (const float*)d_in[6];
  const float* b1     = (const float*)d_in[7];
  const float* w2     = (const float*)d_in[8];
  const float* b2     = (const float*)d_in[9];
  const float* ln2_g  = (const float*)d_in[10];
  const float* ln2_b  = (const float*)d_in[11];
  float* out = (float*)d_out;

  char* ws = (char*)d_ws;
  unsigned short* T_a   = (unsigned short*)(ws);
  unsigned short* T_b   = (unsigned short*)(ws + 8388608);
  unsigned short* x2buf = (unsigned short*)(ws + 16777216);   // bf16 [8192,1024]
  unsigned short* Vtbuf = (unsigned short*)(ws + 33554432);
  unsigned short* Hbuf  = (unsigned short*)(ws + 50331648);
  unsigned short* qkvb  = (unsigned short*)(ws + 67108864);
  unsigned short* h3buf = (unsigned short*)(ws + 50331648);
  unsigned short* h2buf = (unsigned short*)d_out;

  const dim3 tb(32, 8);
  transpose_k<<<dim3(96, 32),  tb, 0, stream>>>(w_qkv,  T_a, 1024, 3072);
  transpose_k<<<dim3(32, 32),  tb, 0, stream>>>(w_proj, T_b, 1024, 1024);
  // h = LN1(x)
  ln_kernel<<<8192, 256, 0, stream>>>(x, 0, ln1_g, ln1_b, Hbuf);
  // qkv = h @ w_qkv   (256x128 tiles: grid = (N/128, M/256))
  gemm_bt<<<dim3(24, 32), 256, 0, stream>>>(Hbuf, T_a, nullptr, nullptr, 0, qkvb, 8192, 3072, 1024, 0, 1, 0);
  transpose_k<<<dim3(128, 32), tb, 0, stream>>>(w1, T_a, 1024, 4096);
  // attention
  vt_k<<<dim3(8, 16, 4), 256, 0, stream>>>(qkvb, Vtbuf);
  attn_mfma<<<dim3(16, 16, 4), 256, 0, stream>>>(qkvb, Vtbuf, Hbuf);
  // x2 = o @ w_proj + b_proj + x  (bf16 out, XCD row-sharing swizzle)
  gemm_bt<<<dim3(32, 8), 256, 0, stream>>>(Hbuf, T_b, b_proj, x, 0, x2buf, 8192, 1024, 1024, 0, 1, 1);
  transpose_k<<<dim3(32, 128), tb, 0, stream>>>(w2, T_b, 4096, 1024);
  // h2 = LN2(x2)
  ln_kernel<<<8192, 256, 0, stream>>>(x2buf, 1, ln2_g, ln2_b, h2buf);
  // h3 = gelu(h2 @ w1 + b1)
  gemm_bt<<<dim3(32, 32), 256, 0, stream>>>(h2buf, T_a, b1, nullptr, 0, h3buf, 8192, 4096, 1024, 1, 1, 0);
  // out = h3 @ w2 + b2 + x2  (fp32 out, swizzle)
  gemm_bt<<<dim3(32, 8), 256, 0, stream>>>(h3buf, T_b, b2, x2buf, 1, out, 8192, 1024, 4096, 0, 0, 1);
}

// Round 4
// 617.000 us; speedup vs baseline: 1.2184x; 1.0897x over previous
//
#include <hip/hip_runtime.h>
#include <cstdint>
#include <cstddef>

// ---------- types / helpers ----------
typedef float  v4f  __attribute__((ext_vector_type(4)));
typedef __bf16 v8bf __attribute__((ext_vector_type(8)));
typedef __bf16 v4bf __attribute__((ext_vector_type(4)));

__device__ __forceinline__ float b2f(unsigned short u) {
  union { unsigned int i; float f; } cv; cv.i = ((unsigned int)u) << 16; return cv.f;
}
__device__ __forceinline__ unsigned short f2b(float f) {
  union { float f; unsigned int i; } cv; cv.f = f;
  unsigned int i = cv.i;
  i += 0x7fffu + ((i >> 16) & 1u);      // round-to-nearest-even
  return (unsigned short)(i >> 16);
}
__device__ __forceinline__ unsigned short f2b_trunc(float f) {
  union { float f; unsigned int i; } cv; cv.f = f;
  return (unsigned short)(cv.i >> 16);  // truncate (cheap); P only
}
// tanh-form GELU: x*sigmoid(1.59577*(x+0.044715x^3)); |err vs erf-GELU| <= ~3e-4.
__device__ __forceinline__ float gelu_fast(float x) {
  const float u = x * (1.5957691216f + 0.07135481627f * x * x);
  return x * (1.0f / (1.0f + __expf(-u)));
}
__device__ __forceinline__ void g2l16(const unsigned short* g, unsigned short* l) {
  __builtin_amdgcn_global_load_lds(
      (const __attribute__((address_space(1))) void*)g,
      (__attribute__((address_space(3))) void*)l,
      16, 0, 0);
}

// ---------- transpose + fp32->bf16 convert: in[R,C] f32 -> out[C,R] bf16 ----------
__global__ __launch_bounds__(256) void transpose_k(const float* __restrict__ in,
                                                   unsigned short* __restrict__ out,
                                                   int R, int C) {
  __shared__ float tile[32][33];
  const int tx = threadIdx.x, ty = threadIdx.y;
  const int r0 = blockIdx.y * 32, c0 = blockIdx.x * 32;
#pragma unroll
  for (int j = 0; j < 4; ++j)
    tile[ty + 8 * j][tx] = in[(size_t)(r0 + ty + 8 * j) * C + c0 + tx];
  __syncthreads();
#pragma unroll
  for (int j = 0; j < 4; ++j)
    out[(size_t)(c0 + ty + 8 * j) * R + r0 + tx] = f2b(tile[tx][ty + 8 * j]);
}

// ---------- layernorm over DIM=1024 (fp32 or bf16 in, bf16 out) ----------
__global__ __launch_bounds__(256) void ln_kernel(const void* __restrict__ xp, int in_bf16,
                                                 const float* __restrict__ g,
                                                 const float* __restrict__ bta,
                                                 unsigned short* __restrict__ out) {
  const int r = blockIdx.x, t = threadIdx.x;
  float v0, v1, v2, v3;
  if (in_bf16) {
    const ushort4 raw = *(const ushort4*)((const unsigned short*)xp + (size_t)r * 1024 + t * 4);
    v0 = b2f(raw.x); v1 = b2f(raw.y); v2 = b2f(raw.z); v3 = b2f(raw.w);
  } else {
    const float4 raw = *(const float4*)((const float*)xp + (size_t)r * 1024 + t * 4);
    v0 = raw.x; v1 = raw.y; v2 = raw.z; v3 = raw.w;
  }
  float s  = v0 + v1 + v2 + v3;
  float s2 = v0 * v0 + v1 * v1 + v2 * v2 + v3 * v3;
#pragma unroll
  for (int off = 32; off > 0; off >>= 1) {
    s  += __shfl_down(s, off);
    s2 += __shfl_down(s2, off);
  }
  __shared__ float red[8];
  const int w = t >> 6, lane = t & 63;
  if (lane == 0) { red[w] = s; red[4 + w] = s2; }
  __syncthreads();
  if (t == 0) {
    float ts = red[0] + red[1] + red[2] + red[3];
    float t2 = red[4] + red[5] + red[6] + red[7];
    float mu = ts * (1.0f / 1024.0f);
    float var = t2 * (1.0f / 1024.0f) - mu * mu;
    red[0] = mu;
    red[1] = rsqrtf(var + 1e-5f);
  }
  __syncthreads();
  const float mu = red[0], rs = red[1];
  const float4 graw = *(const float4*)(g + t * 4);
  const float4 braw = *(const float4*)(bta + t * 4);
  ushort4 o;
  o.x = f2b((v0 - mu) * rs * graw.x + braw.x);
  o.y = f2b((v1 - mu) * rs * graw.y + braw.y);
  o.z = f2b((v2 - mu) * rs * graw.z + braw.z);
  o.w = f2b((v3 - mu) * rs * graw.w + braw.w);
  *(ushort4*)(out + (size_t)r * 1024 + t * 4) = o;
}

// ---------- 8-phase MFMA GEMM (m201 template): C[M,N]=A[M,K]@Bt[N,K]^T ----------
// BM=256, BK=64, 512 threads = 8 waves (2M x 4N), per-wave 128 x (BN/4) output.
// NREP = BN/64: 4 -> BN=256 (4 phases/K-tile), 2 -> BN=128 (2 phases/K-tile).
// LDS: 2 dbuf x (A 256x64 + B BNx64) bf16 = 128/96 KB -> 1 block/CU (by design).
// Per phase: {ds_read subtile || stage one half-tile of kt+1} -> barrier ->
// setprio(1) + 16 MFMA -> barrier. vmcnt(4) ONCE per K-tile (retires kt's loads,
// leaves kt+1's A in flight) - never drained to 0 in the main loop (T4).
// Swizzle (T2, rule 21 both-sides): LDS dest linear (global_load_lds), source
// chunk = (t&7)^(row&7), read chunk = (kq*4+lq)^(lr&7) -> max 2-way (free).
// Buffer safety: kt's staging target = kt-1's read buffer; kt-1's trailing
// collective barrier guarantees all waves finished reading before any stages.
template <int NREP>
__global__ __launch_bounds__(512, 2) void gemm8p(const unsigned short* __restrict__ A,
                                                 const unsigned short* __restrict__ Bt,
                                                 const float* __restrict__ bias,
                                                 const void* __restrict__ res, int res_bf16,
                                                 void* __restrict__ Cout,
                                                 int M, int N, int K, int act, int out_bf16,
                                                 int swap_xy) {
  constexpr int BN = NREP * 64;
  __shared__ __align__(16) unsigned short As[2][256 * 64];
  __shared__ __align__(16) unsigned short Bs[2][BN * 64];
  const int t = threadIdx.x;
  const int lane = t & 63;
  const int lr = lane & 15, lq = lane >> 4;
  const int wid = t >> 6;
  const int wm = wid >> 2, wn = wid & 3;          // wave 128-row half, 64/32-col slot
  const int mb = swap_xy ? blockIdx.x : blockIdx.y;
  const int nb = swap_xy ? blockIdx.y : blockIdx.x;
  const int m0 = mb * 256, n0 = nb * BN;

  // staging geometry: 512 threads x 16B = 64 rows of 64 bf16 per call
  const int srow = t >> 3;                        // 0..63
  const int schunk = (t & 7) ^ (srow & 7);        // pre-swizzled source chunk
  const unsigned short* Agp[4];
  const unsigned short* Bgp[NREP];
#pragma unroll
  for (int j = 0; j < 4; ++j)
    Agp[j] = A + (size_t)(m0 + j * 64 + srow) * K + schunk * 8;
#pragma unroll
  for (int j = 0; j < NREP; ++j)
    Bgp[j] = Bt + (size_t)(n0 + j * 64 + srow) * K + schunk * 8;

  auto stageA = [&](int dbuf, int ko) {
#pragma unroll
    for (int j = 0; j < 4; ++j)
      g2l16(Agp[j] + ko, &As[dbuf][j * 4096 + t * 8]);
  };
  auto stageB = [&](int dbuf, int ko) {
#pragma unroll
    for (int j = 0; j < NREP; ++j)
      g2l16(Bgp[j] + ko, &Bs[dbuf][j * 4096 + t * 8]);
  };
  // swizzled fragment reads (rows stride 128B; XOR spreads 16 rows over 8 chunks)
  auto lda = [&](int dbuf, int mi, int kq) -> v8bf {
    return *(const v8bf*)(&As[dbuf][(wm * 128 + mi * 16 + lr) * 64 +
                                    (((kq * 4 + lq) ^ (lr & 7)) << 3)]);
  };
  auto ldb = [&](int dbuf, int ni, int kq) -> v8bf {
    return *(const v8bf*)(&Bs[dbuf][(wn * (BN / 4) + ni * 16 + lr) * 64 +
                                    (((kq * 4 + lq) ^ (lr & 7)) << 3)]);
  };

  v4f acc[8][NREP];
#pragma unroll
  for (int mi = 0; mi < 8; ++mi)
#pragma unroll
    for (int ni = 0; ni < NREP; ++ni)
      acc[mi][ni] = (v4f){0.f, 0.f, 0.f, 0.f};

  const int NT = K >> 6;
  stageA(0, 0);
  stageB(0, 0);

  for (int kt = 0; kt < NT; ++kt) {
    const int buf = kt & 1, nbuf = buf ^ 1;
    const bool pre = (kt + 1) < NT;
    const int ko = (kt + 1) << 6;

    if constexpr (NREP == 4) {
      v8bf aL[4][2], aH[4][2], bL[2][2], bH[2][2];
      // ---- phase 0: stage A(kt+1); vmcnt; q(miLo x niLo) ----
      if (pre) {
        stageA(nbuf, ko);
        asm volatile("s_waitcnt vmcnt(4)" ::: "memory");
      } else {
        asm volatile("s_waitcnt vmcnt(0)" ::: "memory");
      }
      __builtin_amdgcn_s_barrier();
#pragma unroll
      for (int mi = 0; mi < 4; ++mi) { aL[mi][0] = lda(buf, mi, 0); aL[mi][1] = lda(buf, mi, 1); }
#pragma unroll
      for (int ni = 0; ni < 2; ++ni) { bL[ni][0] = ldb(buf, ni, 0); bL[ni][1] = ldb(buf, ni, 1); }
      __builtin_amdgcn_s_setprio(1);
#pragma unroll
      for (int mi = 0; mi < 4; ++mi)
#pragma unroll
        for (int ni = 0; ni < 2; ++ni)
#pragma unroll
          for (int kq = 0; kq < 2; ++kq)
            acc[mi][ni] = __builtin_amdgcn_mfma_f32_16x16x32_bf16(aL[mi][kq], bL[ni][kq], acc[mi][ni], 0, 0, 0);
      __builtin_amdgcn_s_setprio(0);
      __builtin_amdgcn_s_barrier();
      // ---- phase 1: read B-hi || stage B(kt+1); q(miLo x niHi) ----
#pragma unroll
      for (int ni = 0; ni < 2; ++ni) { bH[ni][0] = ldb(buf, ni + 2, 0); bH[ni][1] = ldb(buf, ni + 2, 1); }
      if (pre) stageB(nbuf, ko);
      __builtin_amdgcn_s_barrier();
      __builtin_amdgcn_s_setprio(1);
#pragma unroll
      for (int mi = 0; mi < 4; ++mi)
#pragma unroll
        for (int ni = 0; ni < 2; ++ni)
#pragma unroll
          for (int kq = 0; kq < 2; ++kq)
            acc[mi][ni + 2] = __builtin_amdgcn_mfma_f32_16x16x32_bf16(aL[mi][kq], bH[ni][kq], acc[mi][ni + 2], 0, 0, 0);
      __builtin_amdgcn_s_setprio(0);
      __builtin_amdgcn_s_barrier();
      // ---- phase 2: read A-hi; q(miHi x niLo) ----
#pragma unroll
      for (int mi = 0; mi < 4; ++mi) { aH[mi][0] = lda(buf, mi + 4, 0); aH[mi][1] = lda(buf, mi + 4, 1); }
      __builtin_amdgcn_s_barrier();
      __builtin_amdgcn_s_setprio(1);
#pragma unroll
      for (int mi = 0; mi < 4; ++mi)
#pragma unroll
        for (int ni = 0; ni < 2; ++ni)
#pragma unroll
          for (int kq = 0; kq < 2; ++kq)
            acc[mi + 4][ni] = __builtin_amdgcn_mfma_f32_16x16x32_bf16(aH[mi][kq], bL[ni][kq], acc[mi + 4][ni], 0, 0, 0);
      __builtin_amdgcn_s_setprio(0);
      __builtin_amdgcn_s_barrier();
      // ---- phase 3: register-only q(miHi x niHi) ----
      __builtin_amdgcn_s_setprio(1);
#pragma unroll
      for (int mi = 0; mi < 4; ++mi)
#pragma unroll
        for (int ni = 0; ni < 2; ++ni)
#pragma unroll
          for (int kq = 0; kq < 2; ++kq)
            acc[mi + 4][ni + 2] = __builtin_amdgcn_mfma_f32_16x16x32_bf16(aH[mi][kq], bH[ni][kq], acc[mi + 4][ni + 2], 0, 0, 0);
      __builtin_amdgcn_s_setprio(0);
      __builtin_amdgcn_s_barrier();
    } else {
      v8bf aL[4][2], aH[4][2], bb[2][2];
      // ---- phase 0: stage A(kt+1); vmcnt; q(miLo x ni all) ----
      if (pre) {
        stageA(nbuf, ko);
        asm volatile("s_waitcnt vmcnt(4)" ::: "memory");
      } else {
        asm volatile("s_waitcnt vmcnt(0)" ::: "memory");
      }
      __builtin_amdgcn_s_barrier();
#pragma unroll
      for (int mi = 0; mi < 4; ++mi) { aL[mi][0] = lda(buf, mi, 0); aL[mi][1] = lda(buf, mi, 1); }
#pragma unroll
      for (int ni = 0; ni < 2; ++ni) { bb[ni][0] = ldb(buf, ni, 0); bb[ni][1] = ldb(buf, ni, 1); }
      __builtin_amdgcn_s_setprio(1);
#pragma unroll
      for (int mi = 0; mi < 4; ++mi)
#pragma unroll
        for (int ni = 0; ni < 2; ++ni)
#pragma unroll
          for (int kq = 0; kq < 2; ++kq)
            acc[mi][ni] = __builtin_amdgcn_mfma_f32_16x16x32_bf16(aL[mi][kq], bb[ni][kq], acc[mi][ni], 0, 0, 0);
      __builtin_amdgcn_s_setprio(0);
      __builtin_amdgcn_s_barrier();
      // ---- phase 1: read A-hi || stage B(kt+1); q(miHi x ni all) ----
#pragma unroll
      for (int mi = 0; mi < 4; ++mi) { aH[mi][0] = lda(buf, mi + 4, 0); aH[mi][1] = lda(buf, mi + 4, 1); }
      if (pre) stageB(nbuf, ko);
      __builtin_amdgcn_s_barrier();
      __builtin_amdgcn_s_setprio(1);
#pragma unroll
      for (int mi = 0; mi < 4; ++mi)
#pragma unroll
        for (int ni = 0; ni < 2; ++ni)
#pragma unroll
          for (int kq = 0; kq < 2; ++kq)
            acc[mi + 4][ni] = __builtin_amdgcn_mfma_f32_16x16x32_bf16(aH[mi][kq], bb[ni][kq], acc[mi + 4][ni], 0, 0, 0);
      __builtin_amdgcn_s_setprio(0);
      __builtin_amdgcn_s_barrier();
    }
  }

  // ---- epilogue ----
  const int wr = wm * 128, wc = wn * (BN / 4);
#pragma unroll
  for (int mi = 0; mi < 8; ++mi) {
#pragma unroll
    for (int ni = 0; ni < NREP; ++ni) {
      const int col = n0 + wc + ni * 16 + lr;
      const float bv = bias ? bias[col] : 0.0f;
#pragma unroll
      for (int r = 0; r < 4; ++r) {
        const int row = m0 + wr + mi * 16 + lq * 4 + r;
        float v = acc[mi][ni][r] + bv;
        if (act) v = gelu_fast(v);
        if (res) {
          v += res_bf16 ? b2f(((const unsigned short*)res)[(size_t)row * N + col])
                        : ((const float*)res)[(size_t)row * N + col];
        }
        if (out_bf16)
          ((unsigned short*)Cout)[(size_t)row * N + col] = f2b(v);
        else
          ((float*)Cout)[(size_t)row * N + col] = v;
      }
    }
  }
}

// ---------- V restage: qkv[token][3072] v-part -> Vt[(b*16+h)*64+d][2048 tokens] ----------
__global__ __launch_bounds__(256) void vt_k(const unsigned short* __restrict__ qkv,
                                            unsigned short* __restrict__ Vt) {
  const int t = threadIdx.x;
  const int n = blockIdx.x * 256 + t, h = blockIdx.y, b = blockIdx.z;
  const size_t src = (size_t)(b * 2048 + n) * 3072 + 2048 + h * 64;
  unsigned short v[64];
#pragma unroll
  for (int j = 0; j < 8; ++j)
    *(uint4*)(v + j * 8) = *(const uint4*)(qkv + src + j * 8);
  const size_t dstbase = ((size_t)(b * 16 + h) * 64) * 2048 + n;
#pragma unroll
  for (int d = 0; d < 64; ++d)
    Vt[dstbase + (size_t)d * 2048] = v[d];
}

// ---------- MFMA flash attention (round-1 verified: LDS-staged K/V, T14 async
// reg-stage split, setprio around MFMA clusters; 119 us measured) ----------
__global__ __launch_bounds__(256, 2) void attn_mfma(const unsigned short* __restrict__ qkv,
                                                    const unsigned short* __restrict__ Vt,
                                                    unsigned short* __restrict__ out) {
  __shared__ __align__(16) unsigned short Ks[64 * 80];
  __shared__ __align__(16) unsigned short Vs[64 * 80];
  __shared__ __align__(16) unsigned short Ps[4][32 * 76];
  const int t = threadIdx.x;
  const int lane = t & 63, w = t >> 6;
  const int lr = lane & 15, lq = lane >> 4;
  const int h = blockIdx.x, b = blockIdx.z;
  const int q0 = blockIdx.y * 128 + w * 32;

  v8bf aq[2][2];
#pragma unroll
  for (int mi = 0; mi < 2; ++mi)
#pragma unroll
    for (int kq = 0; kq < 2; ++kq)
      aq[mi][kq] = *(const v8bf*)(qkv + (size_t)(b * 2048 + q0 + mi * 16 + lr) * 3072
                                  + h * 64 + kq * 32 + lq * 8);

  v4f acc_o[2][4];
  float lsum[2][4];
#pragma unroll
  for (int mi = 0; mi < 2; ++mi)
#pragma unroll
    for (int di = 0; di < 4; ++di)
      acc_o[mi][di] = (v4f){0.f, 0.f, 0.f, 0.f};
#pragma unroll
  for (int mi = 0; mi < 2; ++mi)
#pragma unroll
    for (int r = 0; r < 4; ++r)
      lsum[mi][r] = 0.0f;

  // per-thread K/V staging addresses (2 chunks of 16B each)
  const int sc0 = t, sc1 = t + 256;
  const int kr0 = sc0 >> 3, ko0 = (sc0 & 7) * 8;
  const int kr1 = sc1 >> 3, ko1 = (sc1 & 7) * 8;
  const unsigned short* Kg0 = qkv + (size_t)(b * 2048 + kr0) * 3072 + 1024 + h * 64 + ko0;
  const unsigned short* Kg1 = qkv + (size_t)(b * 2048 + kr1) * 3072 + 1024 + h * 64 + ko1;
  const unsigned short* Vg0 = Vt + ((size_t)(b * 16 + h) * 64 + kr0) * 2048 + ko0;
  const unsigned short* Vg1 = Vt + ((size_t)(b * 16 + h) * 64 + kr1) * 2048 + ko1;

  // prologue: tile 0 into LDS
  uint4 kreg0 = *(const uint4*)(Kg0);
  uint4 kreg1 = *(const uint4*)(Kg1);
  uint4 vreg0 = *(const uint4*)(Vg0);
  uint4 vreg1 = *(const uint4*)(Vg1);
  *(uint4*)(Ks + kr0 * 80 + ko0) = kreg0;
  *(uint4*)(Ks + kr1 * 80 + ko1) = kreg1;
  *(uint4*)(Vs + kr0 * 80 + ko0) = vreg0;
  *(uint4*)(Vs + kr1 * 80 + ko1) = vreg1;
  __syncthreads();

  for (int kt = 0; kt < 32; ++kt) {
    // issue next tile's global loads early; latency hides under compute
    if (kt < 31) {
      const size_t kn = (size_t)(kt + 1) * 64;
      kreg0 = *(const uint4*)(Kg0 + kn * 3072);
      kreg1 = *(const uint4*)(Kg1 + kn * 3072);
      vreg0 = *(const uint4*)(Vg0 + kn);
      vreg1 = *(const uint4*)(Vg1 + kn);
    }

    v4f s_acc[2][4];
#pragma unroll
    for (int mi = 0; mi < 2; ++mi)
#pragma unroll
      for (int ni = 0; ni < 4; ++ni)
        s_acc[mi][ni] = (v4f){0.f, 0.f, 0.f, 0.f};
#pragma unroll
    for (int kq = 0; kq < 2; ++kq) {
      v8bf bk[4];
#pragma unroll
      for (int ni = 0; ni < 4; ++ni)
        bk[ni] = *(const v8bf*)(Ks + (ni * 16 + lr) * 80 + kq * 32 + lq * 8);
      __builtin_amdgcn_s_setprio(1);
#pragma unroll
      for (int mi = 0; mi < 2; ++mi)
#pragma unroll
        for (int ni = 0; ni < 4; ++ni)
          s_acc[mi][ni] = __builtin_amdgcn_mfma_f32_16x16x32_bf16(aq[mi][kq], bk[ni], s_acc[mi][ni], 0, 0, 0);
      __builtin_amdgcn_s_setprio(0);
    }

#pragma unroll
    for (int mi = 0; mi < 2; ++mi)
#pragma unroll
      for (int ni = 0; ni < 4; ++ni)
#pragma unroll
        for (int r = 0; r < 4; ++r) {
          const float p = __expf(s_acc[mi][ni][r] * 0.125f);
          const unsigned short pb = f2b_trunc(p);
          lsum[mi][r] += b2f(pb);
          Ps[w][(mi * 16 + lq * 4 + r) * 76 + ni * 16 + lr] = pb;
        }

#pragma unroll
    for (int ks = 0; ks < 2; ++ks) {
      v8bf ap[2], bv[4];
#pragma unroll
      for (int mi = 0; mi < 2; ++mi) {
        const unsigned short* base = Ps[w] + (mi * 16 + lr) * 76 + ks * 32 + lq * 8;
        const v4bf lo = *(const v4bf*)(base);
        const v4bf hi = *(const v4bf*)(base + 4);
        ap[mi] = __builtin_shufflevector(lo, hi, 0, 1, 2, 3, 4, 5, 6, 7);
      }
#pragma unroll
      for (int di = 0; di < 4; ++di)
        bv[di] = *(const v8bf*)(Vs + (di * 16 + lr) * 80 + ks * 32 + lq * 8);
      __builtin_amdgcn_s_setprio(1);
#pragma unroll
      for (int mi = 0; mi < 2; ++mi)
#pragma unroll
        for (int di = 0; di < 4; ++di)
          acc_o[mi][di] = __builtin_amdgcn_mfma_f32_16x16x32_bf16(ap[mi], bv[di], acc_o[mi][di], 0, 0, 0);
      __builtin_amdgcn_s_setprio(0);
    }

    __syncthreads();            // all waves done reading Ks/Vs
    if (kt < 31) {
      *(uint4*)(Ks + kr0 * 80 + ko0) = kreg0;
      *(uint4*)(Ks + kr1 * 80 + ko1) = kreg1;
      *(uint4*)(Vs + kr0 * 80 + ko0) = vreg0;
      *(uint4*)(Vs + kr1 * 80 + ko1) = vreg1;
    }
    __syncthreads();            // next tile visible
  }

#pragma unroll
  for (int mi = 0; mi < 2; ++mi)
#pragma unroll
    for (int r = 0; r < 4; ++r) {
      float v = lsum[mi][r];
      v += __shfl_xor(v, 1);
      v += __shfl_xor(v, 2);
      v += __shfl_xor(v, 4);
      v += __shfl_xor(v, 8);
      lsum[mi][r] = 1.0f / v;
    }

#pragma unroll
  for (int mi = 0; mi < 2; ++mi)
#pragma unroll
    for (int di = 0; di < 4; ++di)
#pragma unroll
      for (int r = 0; r < 4; ++r)
        out[(size_t)(b * 2048 + q0 + mi * 16 + lq * 4 + r) * 1024 + h * 64 + di * 16 + lr] =
            f2b(acc_o[mi][di][r] * lsum[mi][r]);
}

// ---------- launch ----------
// ws layout (112 MiB): T_a [0,8M) wt_qkv->wt_w1; T_b [8,16M) wt_proj->wt_w2;
// x2 bf16 [16,32M); Vt [32,48M); H [48,64M) h->o; qkv [64,112M);
// h3 [48,112M) overlays dead H+qkv; h2 bf16 in d_out scratch.
extern "C" void kernel_launch(void* const* d_in, const int* in_sizes, int n_in,
                              void* d_out, int out_size, void* d_ws, size_t ws_size,
                              hipStream_t stream) {
  (void)in_sizes; (void)n_in; (void)out_size; (void)ws_size;
  const float* x      = (const float*)d_in[0];
  const float* w_qkv  = (const float*)d_in[1];
  const float* w_proj = (const float*)d_in[2];
  const float* b_proj = (const float*)d_in[3];
  const float* ln1_g  = (const float*)d_in[4];
  const float* ln1_b  = (const float*)d_in[5];
  const float* w1     = (const float*)d_in[6];
  const float* b1     = (const float*)d_in[7];
  const float* w2     = (const float*)d_in[8];
  const float* b2     = (const float*)d_in[9];
  const float* ln2_g  = (const float*)d_in[10];
  const float* ln2_b  = (const float*)d_in[11];
  float* out = (float*)d_out;

  char* ws = (char*)d_ws;
  unsigned short* T_a   = (unsigned short*)(ws);
  unsigned short* T_b   = (unsigned short*)(ws + 8388608);
  unsigned short* x2buf = (unsigned short*)(ws + 16777216);   // bf16 [8192,1024]
  unsigned short* Vtbuf = (unsigned short*)(ws + 33554432);
  unsigned short* Hbuf  = (unsigned short*)(ws + 50331648);
  unsigned short* qkvb  = (unsigned short*)(ws + 67108864);
  unsigned short* h3buf = (unsigned short*)(ws + 50331648);
  unsigned short* h2buf = (unsigned short*)d_out;

  const dim3 tb(32, 8);
  transpose_k<<<dim3(96, 32),  tb, 0, stream>>>(w_qkv,  T_a, 1024, 3072);
  transpose_k<<<dim3(32, 32),  tb, 0, stream>>>(w_proj, T_b, 1024, 1024);
  // h = LN1(x)
  ln_kernel<<<8192, 256, 0, stream>>>(x, 0, ln1_g, ln1_b, Hbuf);
  // qkv = h @ w_qkv   (BM=256, BN=256: grid (N/256, M/256))
  gemm8p<4><<<dim3(12, 32), 512, 0, stream>>>(Hbuf, T_a, nullptr, nullptr, 0, qkvb, 8192, 3072, 1024, 0, 1, 0);
  transpose_k<<<dim3(128, 32), tb, 0, stream>>>(w1, T_a, 1024, 4096);
  // attention
  vt_k<<<dim3(8, 16, 4), 256, 0, stream>>>(qkvb, Vtbuf);
  attn_mfma<<<dim3(16, 16, 4), 256, 0, stream>>>(qkvb, Vtbuf, Hbuf);
  // x2 = o @ w_proj + b_proj + x  (BN=128: grid (M/256, N/128) swapped, 256 blocks)
  gemm8p<2><<<dim3(32, 8), 512, 0, stream>>>(Hbuf, T_b, b_proj, x, 0, x2buf, 8192, 1024, 1024, 0, 1, 1);
  transpose_k<<<dim3(32, 128), tb, 0, stream>>>(w2, T_b, 4096, 1024);
  // h2 = LN2(x2)
  ln_kernel<<<8192, 256, 0, stream>>>(x2buf, 1, ln2_g, ln2_b, h2buf);
  // h3 = gelu(h2 @ w1 + b1)
  gemm8p<4><<<dim3(16, 32), 512, 0, stream>>>(h2buf, T_a, b1, nullptr, 0, h3buf, 8192, 4096, 1024, 1, 1, 0);
  // out = h3 @ w2 + b2 + x2  (BN=128, K=4096)
  gemm8p<2><<<dim3(32, 8), 512, 0, stream>>>(h3buf, T_b, b2, x2buf, 1, out, 8192, 1024, 4096, 0, 0, 1);
}

// Round 5
// 599.407 us; speedup vs baseline: 1.2542x; 1.0294x over previous
//
#include <hip/hip_runtime.h>
#include <cstdint>
#include <cstddef>

// ---------- types / helpers ----------
typedef float  v4f  __attribute__((ext_vector_type(4)));
typedef __bf16 v8bf __attribute__((ext_vector_type(8)));
typedef __bf16 v4bf __attribute__((ext_vector_type(4)));

__device__ __forceinline__ float b2f(unsigned short u) {
  union { unsigned int i; float f; } cv; cv.i = ((unsigned int)u) << 16; return cv.f;
}
__device__ __forceinline__ unsigned short f2b(float f) {
  union { float f; unsigned int i; } cv; cv.f = f;
  unsigned int i = cv.i;
  i += 0x7fffu + ((i >> 16) & 1u);      // round-to-nearest-even
  return (unsigned short)(i >> 16);
}
__device__ __forceinline__ unsigned short f2b_trunc(float f) {
  union { float f; unsigned int i; } cv; cv.f = f;
  return (unsigned short)(cv.i >> 16);  // truncate (cheap); P only
}
// tanh-form GELU: x*sigmoid(1.59577*(x+0.044715x^3)); |err vs erf-GELU| <= ~3e-4.
__device__ __forceinline__ float gelu_fast(float x) {
  const float u = x * (1.5957691216f + 0.07135481627f * x * x);
  return x * (1.0f / (1.0f + __expf(-u)));
}
__device__ __forceinline__ void g2l16(const unsigned short* g, unsigned short* l) {
  __builtin_amdgcn_global_load_lds(
      (const __attribute__((address_space(1))) void*)g,
      (__attribute__((address_space(3))) void*)l,
      16, 0, 0);
}

// ---------- transpose + fp32->bf16 convert: in[R,C] f32 -> out[C,R] bf16 ----------
__global__ __launch_bounds__(256) void transpose_k(const float* __restrict__ in,
                                                   unsigned short* __restrict__ out,
                                                   int R, int C) {
  __shared__ float tile[32][33];
  const int tx = threadIdx.x, ty = threadIdx.y;
  const int r0 = blockIdx.y * 32, c0 = blockIdx.x * 32;
#pragma unroll
  for (int j = 0; j < 4; ++j)
    tile[ty + 8 * j][tx] = in[(size_t)(r0 + ty + 8 * j) * C + c0 + tx];
  __syncthreads();
#pragma unroll
  for (int j = 0; j < 4; ++j)
    out[(size_t)(c0 + ty + 8 * j) * R + r0 + tx] = f2b(tile[tx][ty + 8 * j]);
}

// ---------- layernorm over DIM=1024 (fp32 or bf16 in, bf16 out) ----------
__global__ __launch_bounds__(256) void ln_kernel(const void* __restrict__ xp, int in_bf16,
                                                 const float* __restrict__ g,
                                                 const float* __restrict__ bta,
                                                 unsigned short* __restrict__ out) {
  const int r = blockIdx.x, t = threadIdx.x;
  float v0, v1, v2, v3;
  if (in_bf16) {
    const ushort4 raw = *(const ushort4*)((const unsigned short*)xp + (size_t)r * 1024 + t * 4);
    v0 = b2f(raw.x); v1 = b2f(raw.y); v2 = b2f(raw.z); v3 = b2f(raw.w);
  } else {
    const float4 raw = *(const float4*)((const float*)xp + (size_t)r * 1024 + t * 4);
    v0 = raw.x; v1 = raw.y; v2 = raw.z; v3 = raw.w;
  }
  float s  = v0 + v1 + v2 + v3;
  float s2 = v0 * v0 + v1 * v1 + v2 * v2 + v3 * v3;
#pragma unroll
  for (int off = 32; off > 0; off >>= 1) {
    s  += __shfl_down(s, off);
    s2 += __shfl_down(s2, off);
  }
  __shared__ float red[8];
  const int w = t >> 6, lane = t & 63;
  if (lane == 0) { red[w] = s; red[4 + w] = s2; }
  __syncthreads();
  if (t == 0) {
    float ts = red[0] + red[1] + red[2] + red[3];
    float t2 = red[4] + red[5] + red[6] + red[7];
    float mu = ts * (1.0f / 1024.0f);
    float var = t2 * (1.0f / 1024.0f) - mu * mu;
    red[0] = mu;
    red[1] = rsqrtf(var + 1e-5f);
  }
  __syncthreads();
  const float mu = red[0], rs = red[1];
  const float4 graw = *(const float4*)(g + t * 4);
  const float4 braw = *(const float4*)(bta + t * 4);
  ushort4 o;
  o.x = f2b((v0 - mu) * rs * graw.x + braw.x);
  o.y = f2b((v1 - mu) * rs * graw.y + braw.y);
  o.z = f2b((v2 - mu) * rs * graw.z + braw.z);
  o.w = f2b((v3 - mu) * rs * graw.w + braw.w);
  *(ushort4*)(out + (size_t)r * 1024 + t * 4) = o;
}

// ---------- MFMA GEMM: C[M,N] = A[M,K] @ Bt[N,K]^T (+bias)(+gelu)(+res) ----------
// Verified round-2 structure: dist-2 pipeline (3 LDS bufs, counted vmcnt across raw
// barriers) + chunk-XOR swizzle (T2, rule 21 both-sides).
// NEW: bijective XCD-chunked block mapping (T1/m204). 1D grid; assume HW round-robins
// bid%8 across XCDs. Remap r=(bid&7)*(nwg/8)+(bid>>3) gives each XCD a contiguous
// range; decode r chunk-major so one XCD owns (NBC nb-columns) x (all mb rows):
// per-XCD B working set = NBC*128*K*2B <= 1MB (L2-resident), A panels L3-resident.
// NBC chosen per call so chunk width MBt*NBC divides nwg/8 exactly.
__global__ __launch_bounds__(256, 2) void gemm_bt(const unsigned short* __restrict__ A,
                                                  const unsigned short* __restrict__ Bt,
                                                  const float* __restrict__ bias,
                                                  const void* __restrict__ res, int res_bf16,
                                                  void* __restrict__ Cout,
                                                  int M, int N, int K, int act, int out_bf16,
                                                  int NBC) {
  __shared__ __align__(16) unsigned short As[3][128 * 32];
  __shared__ __align__(16) unsigned short Bs[3][128 * 32];
  const int t = threadIdx.x;
  const int lane = t & 63, w = t >> 6;
  const int wr = (w >> 1) * 64, wc = (w & 1) * 64;
  const int lr = lane & 15, lq = lane >> 4;

  // ---- XCD-chunked block decode ----
  const int nwg = gridDim.x;
  const int bid = blockIdx.x;
  const int q8 = nwg >> 3;
  const int r = (bid & 7) * q8 + (bid >> 3);
  const int MBt = M >> 7;
  const int chunkW = MBt * NBC;
  const int c = r / chunkW, ci = r - c * chunkW;
  const int mb = ci / NBC;
  const int nb = c * NBC + (ci - (ci / NBC) * NBC);
  const int m0 = mb * 128, n0 = nb * 128;

  // staging: chunk cc -> LDS linear (row=cc>>2, chunk=cc&3); source chunk=(cc&3)^((row>>1)&3)
  const int c0 = t, c1 = t + 256;
  const int r0 = c0 >> 2, o0 = (((c0 & 3) ^ ((c0 >> 3) & 3)) << 3);
  const int r1 = c1 >> 2, o1 = (((c1 & 3) ^ ((c1 >> 3) & 3)) << 3);
  const unsigned short* Ag0 = A  + (size_t)(m0 + r0) * K + o0;
  const unsigned short* Ag1 = A  + (size_t)(m0 + r1) * K + o1;
  const unsigned short* Bg0 = Bt + (size_t)(n0 + r0) * K + o0;
  const unsigned short* Bg1 = Bt + (size_t)(n0 + r1) * K + o1;

  // read-side swizzled chunk offset (row = ..+lr => s(row) = (lr>>1)&3, invariant)
  const int ra = ((lq ^ ((lr >> 1) & 3)) << 3);

  v4f acc[4][4];
#pragma unroll
  for (int mi = 0; mi < 4; ++mi)
#pragma unroll
    for (int ni = 0; ni < 4; ++ni)
      acc[mi][ni] = (v4f){0.f, 0.f, 0.f, 0.f};

  const int nt = K >> 5;
  // prologue: stage tiles 0 and 1
  g2l16(Ag0, &As[0][c0 * 8]); g2l16(Bg0, &Bs[0][c0 * 8]);
  g2l16(Ag1, &As[0][c1 * 8]); g2l16(Bg1, &Bs[0][c1 * 8]);
  if (nt > 1) {
    g2l16(Ag0 + 32, &As[1][c0 * 8]); g2l16(Bg0 + 32, &Bs[1][c0 * 8]);
    g2l16(Ag1 + 32, &As[1][c1 * 8]); g2l16(Bg1 + 32, &Bs[1][c1 * 8]);
  }

  int bi = 0;
  for (int tt = 0; tt < nt; ++tt) {
    const int pf = tt + 2;
    if (pf < nt) {
      const int ko = pf << 5;
      const int pb = pf % 3;
      g2l16(Ag0 + ko, &As[pb][c0 * 8]); g2l16(Bg0 + ko, &Bs[pb][c0 * 8]);
      g2l16(Ag1 + ko, &As[pb][c1 * 8]); g2l16(Bg1 + ko, &Bs[pb][c1 * 8]);
      asm volatile("s_waitcnt vmcnt(8)" ::: "memory");
    } else if (tt + 1 < nt) {
      asm volatile("s_waitcnt vmcnt(4)" ::: "memory");
    } else {
      asm volatile("s_waitcnt vmcnt(0)" ::: "memory");
    }
    __builtin_amdgcn_s_barrier();
    asm volatile("" ::: "memory");

    v8bf af[4], bfr[4];
#pragma unroll
    for (int i = 0; i < 4; ++i) {
      af[i]  = *(const v8bf*)(&As[bi][(wr + i * 16 + lr) * 32 + ra]);
      bfr[i] = *(const v8bf*)(&Bs[bi][(wc + i * 16 + lr) * 32 + ra]);
    }
#pragma unroll
    for (int mi = 0; mi < 4; ++mi)
#pragma unroll
      for (int ni = 0; ni < 4; ++ni)
        acc[mi][ni] = __builtin_amdgcn_mfma_f32_16x16x32_bf16(af[mi], bfr[ni], acc[mi][ni], 0, 0, 0);

    asm volatile("" ::: "memory");
    __builtin_amdgcn_s_barrier();
    bi = (bi == 2) ? 0 : bi + 1;
  }

#pragma unroll
  for (int mi = 0; mi < 4; ++mi) {
#pragma unroll
    for (int ni = 0; ni < 4; ++ni) {
      const int col = n0 + wc + ni * 16 + lr;
      const float bv = bias ? bias[col] : 0.0f;
#pragma unroll
      for (int rr = 0; rr < 4; ++rr) {
        const int row = m0 + wr + mi * 16 + lq * 4 + rr;
        float v = acc[mi][ni][rr] + bv;
        if (act) v = gelu_fast(v);
        if (res) {
          v += res_bf16 ? b2f(((const unsigned short*)res)[(size_t)row * N + col])
                        : ((const float*)res)[(size_t)row * N + col];
        }
        if (out_bf16)
          ((unsigned short*)Cout)[(size_t)row * N + col] = f2b(v);
        else
          ((float*)Cout)[(size_t)row * N + col] = v;
      }
    }
  }
}

// ---------- V restage: qkv[token][3072] v-part -> Vt[(b*16+h)*64+d][2048 tokens] ----------
__global__ __launch_bounds__(256) void vt_k(const unsigned short* __restrict__ qkv,
                                            unsigned short* __restrict__ Vt) {
  const int t = threadIdx.x;
  const int n = blockIdx.x * 256 + t, h = blockIdx.y, b = blockIdx.z;
  const size_t src = (size_t)(b * 2048 + n) * 3072 + 2048 + h * 64;
  unsigned short v[64];
#pragma unroll
  for (int j = 0; j < 8; ++j)
    *(uint4*)(v + j * 8) = *(const uint4*)(qkv + src + j * 8);
  const size_t dstbase = ((size_t)(b * 16 + h) * 64) * 2048 + n;
#pragma unroll
  for (int d = 0; d < 64; ++d)
    Vt[dstbase + (size_t)d * 2048] = v[d];
}

// ---------- MFMA flash attention (round-1 verified: LDS-staged K/V, T14 async
// reg-stage split, setprio around MFMA clusters; 119 us measured) ----------
__global__ __launch_bounds__(256, 2) void attn_mfma(const unsigned short* __restrict__ qkv,
                                                    const unsigned short* __restrict__ Vt,
                                                    unsigned short* __restrict__ out) {
  __shared__ __align__(16) unsigned short Ks[64 * 80];
  __shared__ __align__(16) unsigned short Vs[64 * 80];
  __shared__ __align__(16) unsigned short Ps[4][32 * 76];
  const int t = threadIdx.x;
  const int lane = t & 63, w = t >> 6;
  const int lr = lane & 15, lq = lane >> 4;
  const int h = blockIdx.x, b = blockIdx.z;
  const int q0 = blockIdx.y * 128 + w * 32;

  v8bf aq[2][2];
#pragma unroll
  for (int mi = 0; mi < 2; ++mi)
#pragma unroll
    for (int kq = 0; kq < 2; ++kq)
      aq[mi][kq] = *(const v8bf*)(qkv + (size_t)(b * 2048 + q0 + mi * 16 + lr) * 3072
                                  + h * 64 + kq * 32 + lq * 8);

  v4f acc_o[2][4];
  float lsum[2][4];
#pragma unroll
  for (int mi = 0; mi < 2; ++mi)
#pragma unroll
    for (int di = 0; di < 4; ++di)
      acc_o[mi][di] = (v4f){0.f, 0.f, 0.f, 0.f};
#pragma unroll
  for (int mi = 0; mi < 2; ++mi)
#pragma unroll
    for (int r = 0; r < 4; ++r)
      lsum[mi][r] = 0.0f;

  // per-thread K/V staging addresses (2 chunks of 16B each)
  const int sc0 = t, sc1 = t + 256;
  const int kr0 = sc0 >> 3, ko0 = (sc0 & 7) * 8;
  const int kr1 = sc1 >> 3, ko1 = (sc1 & 7) * 8;
  const unsigned short* Kg0 = qkv + (size_t)(b * 2048 + kr0) * 3072 + 1024 + h * 64 + ko0;
  const unsigned short* Kg1 = qkv + (size_t)(b * 2048 + kr1) * 3072 + 1024 + h * 64 + ko1;
  const unsigned short* Vg0 = Vt + ((size_t)(b * 16 + h) * 64 + kr0) * 2048 + ko0;
  const unsigned short* Vg1 = Vt + ((size_t)(b * 16 + h) * 64 + kr1) * 2048 + ko1;

  // prologue: tile 0 into LDS
  uint4 kreg0 = *(const uint4*)(Kg0);
  uint4 kreg1 = *(const uint4*)(Kg1);
  uint4 vreg0 = *(const uint4*)(Vg0);
  uint4 vreg1 = *(const uint4*)(Vg1);
  *(uint4*)(Ks + kr0 * 80 + ko0) = kreg0;
  *(uint4*)(Ks + kr1 * 80 + ko1) = kreg1;
  *(uint4*)(Vs + kr0 * 80 + ko0) = vreg0;
  *(uint4*)(Vs + kr1 * 80 + ko1) = vreg1;
  __syncthreads();

  for (int kt = 0; kt < 32; ++kt) {
    // issue next tile's global loads early; latency hides under compute
    if (kt < 31) {
      const size_t kn = (size_t)(kt + 1) * 64;
      kreg0 = *(const uint4*)(Kg0 + kn * 3072);
      kreg1 = *(const uint4*)(Kg1 + kn * 3072);
      vreg0 = *(const uint4*)(Vg0 + kn);
      vreg1 = *(const uint4*)(Vg1 + kn);
    }

    v4f s_acc[2][4];
#pragma unroll
    for (int mi = 0; mi < 2; ++mi)
#pragma unroll
      for (int ni = 0; ni < 4; ++ni)
        s_acc[mi][ni] = (v4f){0.f, 0.f, 0.f, 0.f};
#pragma unroll
    for (int kq = 0; kq < 2; ++kq) {
      v8bf bk[4];
#pragma unroll
      for (int ni = 0; ni < 4; ++ni)
        bk[ni] = *(const v8bf*)(Ks + (ni * 16 + lr) * 80 + kq * 32 + lq * 8);
      __builtin_amdgcn_s_setprio(1);
#pragma unroll
      for (int mi = 0; mi < 2; ++mi)
#pragma unroll
        for (int ni = 0; ni < 4; ++ni)
          s_acc[mi][ni] = __builtin_amdgcn_mfma_f32_16x16x32_bf16(aq[mi][kq], bk[ni], s_acc[mi][ni], 0, 0, 0);
      __builtin_amdgcn_s_setprio(0);
    }

#pragma unroll
    for (int mi = 0; mi < 2; ++mi)
#pragma unroll
      for (int ni = 0; ni < 4; ++ni)
#pragma unroll
        for (int r = 0; r < 4; ++r) {
          const float p = __expf(s_acc[mi][ni][r] * 0.125f);
          const unsigned short pb = f2b_trunc(p);
          lsum[mi][r] += b2f(pb);
          Ps[w][(mi * 16 + lq * 4 + r) * 76 + ni * 16 + lr] = pb;
        }

#pragma unroll
    for (int ks = 0; ks < 2; ++ks) {
      v8bf ap[2], bv[4];
#pragma unroll
      for (int mi = 0; mi < 2; ++mi) {
        const unsigned short* base = Ps[w] + (mi * 16 + lr) * 76 + ks * 32 + lq * 8;
        const v4bf lo = *(const v4bf*)(base);
        const v4bf hi = *(const v4bf*)(base + 4);
        ap[mi] = __builtin_shufflevector(lo, hi, 0, 1, 2, 3, 4, 5, 6, 7);
      }
#pragma unroll
      for (int di = 0; di < 4; ++di)
        bv[di] = *(const v8bf*)(Vs + (di * 16 + lr) * 80 + ks * 32 + lq * 8);
      __builtin_amdgcn_s_setprio(1);
#pragma unroll
      for (int mi = 0; mi < 2; ++mi)
#pragma unroll
        for (int di = 0; di < 4; ++di)
          acc_o[mi][di] = __builtin_amdgcn_mfma_f32_16x16x32_bf16(ap[mi], bv[di], acc_o[mi][di], 0, 0, 0);
      __builtin_amdgcn_s_setprio(0);
    }

    __syncthreads();            // all waves done reading Ks/Vs
    if (kt < 31) {
      *(uint4*)(Ks + kr0 * 80 + ko0) = kreg0;
      *(uint4*)(Ks + kr1 * 80 + ko1) = kreg1;
      *(uint4*)(Vs + kr0 * 80 + ko0) = vreg0;
      *(uint4*)(Vs + kr1 * 80 + ko1) = vreg1;
    }
    __syncthreads();            // next tile visible
  }

#pragma unroll
  for (int mi = 0; mi < 2; ++mi)
#pragma unroll
    for (int r = 0; r < 4; ++r) {
      float v = lsum[mi][r];
      v += __shfl_xor(v, 1);
      v += __shfl_xor(v, 2);
      v += __shfl_xor(v, 4);
      v += __shfl_xor(v, 8);
      lsum[mi][r] = 1.0f / v;
    }

#pragma unroll
  for (int mi = 0; mi < 2; ++mi)
#pragma unroll
    for (int di = 0; di < 4; ++di)
#pragma unroll
      for (int r = 0; r < 4; ++r)
        out[(size_t)(b * 2048 + q0 + mi * 16 + lq * 4 + r) * 1024 + h * 64 + di * 16 + lr] =
            f2b(acc_o[mi][di][r] * lsum[mi][r]);
}

// ---------- launch ----------
// ws layout (112 MiB): T_a [0,8M) wt_qkv->wt_w1; T_b [8,16M) wt_proj->wt_w2;
// x2 bf16 [16,32M); Vt [32,48M); H [48,64M) h->o; qkv [64,112M);
// h3 [48,112M) overlays dead H+qkv; h2 bf16 in d_out scratch.
extern "C" void kernel_launch(void* const* d_in, const int* in_sizes, int n_in,
                              void* d_out, int out_size, void* d_ws, size_t ws_size,
                              hipStream_t stream) {
  (void)in_sizes; (void)n_in; (void)out_size; (void)ws_size;
  const float* x      = (const float*)d_in[0];
  const float* w_qkv  = (const float*)d_in[1];
  const float* w_proj = (const float*)d_in[2];
  const float* b_proj = (const float*)d_in[3];
  const float* ln1_g  = (const float*)d_in[4];
  const float* ln1_b  = (const float*)d_in[5];
  const float* w1     = (const float*)d_in[6];
  const float* b1     = (const float*)d_in[7];
  const float* w2     = (const float*)d_in[8];
  const float* b2     = (const float*)d_in[9];
  const float* ln2_g  = (const float*)d_in[10];
  const float* ln2_b  = (const float*)d_in[11];
  float* out = (float*)d_out;

  char* ws = (char*)d_ws;
  unsigned short* T_a   = (unsigned short*)(ws);
  unsigned short* T_b   = (unsigned short*)(ws + 8388608);
  unsigned short* x2buf = (unsigned short*)(ws + 16777216);   // bf16 [8192,1024]
  unsigned short* Vtbuf = (unsigned short*)(ws + 33554432);
  unsigned short* Hbuf  = (unsigned short*)(ws + 50331648);
  unsigned short* qkvb  = (unsigned short*)(ws + 67108864);
  unsigned short* h3buf = (unsigned short*)(ws + 50331648);
  unsigned short* h2buf = (unsigned short*)d_out;

  const dim3 tb(32, 8);
  transpose_k<<<dim3(96, 32),  tb, 0, stream>>>(w_qkv,  T_a, 1024, 3072);
  transpose_k<<<dim3(32, 32),  tb, 0, stream>>>(w_proj, T_b, 1024, 1024);
  // h = LN1(x)
  ln_kernel<<<8192, 256, 0, stream>>>(x, 0, ln1_g, ln1_b, Hbuf);
  // qkv = h @ w_qkv   (nwg=1536, q8=192, NBC=3 -> chunkW=192=q8: 1 chunk/XCD)
  gemm_bt<<<1536, 256, 0, stream>>>(Hbuf, T_a, nullptr, nullptr, 0, qkvb, 8192, 3072, 1024, 0, 1, 3);
  transpose_k<<<dim3(128, 32), tb, 0, stream>>>(w1, T_a, 1024, 4096);
  // attention
  vt_k<<<dim3(8, 16, 4), 256, 0, stream>>>(qkvb, Vtbuf);
  attn_mfma<<<dim3(16, 16, 4), 256, 0, stream>>>(qkvb, Vtbuf, Hbuf);
  // x2 = o @ w_proj + b_proj + x  (nwg=512, q8=64, NBC=1 -> 1 nb-column/XCD)
  gemm_bt<<<512, 256, 0, stream>>>(Hbuf, T_b, b_proj, x, 0, x2buf, 8192, 1024, 1024, 0, 1, 1);
  transpose_k<<<dim3(32, 128), tb, 0, stream>>>(w2, T_b, 4096, 1024);
  // h2 = LN2(x2)
  ln_kernel<<<8192, 256, 0, stream>>>(x2buf, 1, ln2_g, ln2_b, h2buf);
  // h3 = gelu(h2 @ w1 + b1)  (nwg=2048, q8=256, NBC=4 -> chunkW=256=q8)
  gemm_bt<<<2048, 256, 0, stream>>>(h2buf, T_a, b1, nullptr, 0, h3buf, 8192, 4096, 1024, 1, 1, 4);
  // out = h3 @ w2 + b2 + x2  (nwg=512, q8=64, NBC=1)
  gemm_bt<<<512, 256, 0, stream>>>(h3buf, T_b, b2, x2buf, 1, out, 8192, 1024, 4096, 0, 0, 1);
}